// Round 2
// baseline (528.665 us; speedup 1.0000x reference)
//
#include <hip/hip_runtime.h>
#include <hip/hip_cooperative_groups.h>

namespace cg = cooperative_groups;

#define N_NODES 100000
#define N_EDGES 640000
#define HIDDEN  128
#define EPS     1e-6f

// ---------------------------------------------------------------------------
// One cooperative kernel, three phases separated by grid syncs.
//
// Phase A (block-local, no sync needed): u[k] = sum_j att_w[j]*W[j,k],
//   v[k] = sum_j att_w[128+j]*W[j,k], c = (att1+att2).b. Every block computes
//   its own copy (W is 64 KB -> L2-hit after the first block per XCD); each
//   thread then holds its float4 slice of u/v in REGISTERS for phases B+D.
// Phase B: p_i = u.x_i, q_i = v.x_i, nacc_i = 0  (2 nodes per wave, float4).
// Phase C: per edge, a = exp(leaky_relu(p[src]+q[dst]+c)); atomicAdd nacc[dst].
// Phase D: y = relu(x/n')+x ; out = norm_w * y * rsqrt(mean(y^2)+eps) + norm_b.
// ---------------------------------------------------------------------------
__global__ __launch_bounds__(256, 4) void fused_gat(
    const float* __restrict__ x,
    const float* __restrict__ W,
    const float* __restrict__ b,
    const float* __restrict__ att_w,
    const float* __restrict__ norm_w,
    const float* __restrict__ norm_b,
    const int*   __restrict__ e,
    float* __restrict__ p,
    float* __restrict__ q,
    float* __restrict__ nacc,
    float* __restrict__ out)
{
    cg::grid_group grid = cg::this_grid();

    __shared__ float part_u[2][HIDDEN];
    __shared__ float part_v[2][HIDDEN];
    __shared__ __align__(16) float uv_s[2 * HIDDEN];   // u then v
    __shared__ float c_s;

    const int tid = threadIdx.x;

    // ---------------- Phase A: block-local u, v, c ----------------
    {
        const int k  = tid & 127;
        const int jh = tid >> 7;            // 0 or 1: which half of j-range
        float su = 0.f, sv = 0.f;
        #pragma unroll 8
        for (int jj = 0; jj < 64; ++jj) {
            int j = jh * 64 + jj;           // wave-uniform -> att_w via s_load
            float w = W[j * HIDDEN + k];    // coalesced 512B per j
            su += att_w[j] * w;
            sv += att_w[HIDDEN + j] * w;
        }
        part_u[jh][k] = su;
        part_v[jh][k] = sv;

        if (tid < 64) {                     // c in parallel, wave 0
            int t0 = tid, t1 = tid + 64;
            float t = (att_w[t0] + att_w[HIDDEN + t0]) * b[t0]
                    + (att_w[t1] + att_w[HIDDEN + t1]) * b[t1];
            #pragma unroll
            for (int off = 32; off > 0; off >>= 1) t += __shfl_xor(t, off);
            if (tid == 0) c_s = t;
        }
        __syncthreads();
        if (tid < HIDDEN) {
            uv_s[tid]          = part_u[0][tid] + part_u[1][tid];
            uv_s[HIDDEN + tid] = part_v[0][tid] + part_v[1][tid];
        }
        __syncthreads();
    }

    const int lane = tid & 63;
    const int half = lane >> 5;             // which of the wave's 2 nodes
    const int sub  = lane & 31;             // float4 slot within a 128-row
    const float4 u4 = ((const float4*)uv_s)[sub];
    const float4 v4 = ((const float4*)(uv_s + HIDDEN))[sub];
    const float  cc = c_s;

    const int gsize  = (int)(gridDim.x * blockDim.x);
    const int gtid   = (int)(blockIdx.x * blockDim.x) + tid;
    const int nwaves = gsize >> 6;
    const int wid    = gtid >> 6;

    // ---------------- Phase B: p, q, nacc=0 ----------------
    for (int node = wid * 2 + half; node < N_NODES; node += nwaves * 2) {
        float4 xv = ((const float4*)(x + (size_t)node * HIDDEN))[sub];
        float sp = xv.x * u4.x + xv.y * u4.y + xv.z * u4.z + xv.w * u4.w;
        float sq = xv.x * v4.x + xv.y * v4.y + xv.z * v4.z + xv.w * v4.w;
        #pragma unroll
        for (int off = 16; off > 0; off >>= 1) {
            sp += __shfl_xor(sp, off);
            sq += __shfl_xor(sq, off);
        }
        if (sub == 0) {
            p[node]    = sp;
            q[node]    = sq;
            nacc[node] = 0.f;
        }
    }

    __threadfence();        // release: write back p/q/nacc dirty lines
    grid.sync();
    __threadfence();        // acquire: invalidate stale copies

    // ---------------- Phase C: edges (2 per thread via int4) ----------------
    for (int i = gtid; i < N_EDGES / 2; i += gsize) {
        int4 ed = ((const int4*)e)[i];      // (src0,dst0,src1,dst1)
        float s0 = p[ed.x] + q[ed.y] + cc;
        float s1 = p[ed.z] + q[ed.w] + cc;
        s0 = s0 > 0.f ? s0 : 0.2f * s0;
        s1 = s1 > 0.f ? s1 : 0.2f * s1;
        atomicAdd(&nacc[ed.y], expf(s0));
        atomicAdd(&nacc[ed.w], expf(s1));
    }

    __threadfence();
    grid.sync();
    __threadfence();

    // ---------------- Phase D: final ----------------
    for (int node = wid * 2 + half; node < N_NODES; node += nwaves * 2) {
        float nn    = nacc[node];
        float inv_n = 1.f / (nn == 0.f ? 1.f : nn);

        float4 xv = ((const float4*)(x + (size_t)node * HIDDEN))[sub];
        float4 y;
        {
            float h;
            h = xv.x * inv_n; h = h > 0.f ? h : 0.f; y.x = h + xv.x;
            h = xv.y * inv_n; h = h > 0.f ? h : 0.f; y.y = h + xv.y;
            h = xv.z * inv_n; h = h > 0.f ? h : 0.f; y.z = h + xv.z;
            h = xv.w * inv_n; h = h > 0.f ? h : 0.f; y.w = h + xv.w;
        }

        float ss = y.x * y.x + y.y * y.y + y.z * y.z + y.w * y.w;
        #pragma unroll
        for (int off = 16; off > 0; off >>= 1) ss += __shfl_xor(ss, off);
        float inv_rms = rsqrtf(ss * (1.f / HIDDEN) + EPS);

        float4 wv = ((const float4*)norm_w)[sub];
        float4 bv = ((const float4*)norm_b)[sub];
        float4 ov;
        ov.x = wv.x * (y.x * inv_rms) + bv.x;
        ov.y = wv.y * (y.y * inv_rms) + bv.y;
        ov.z = wv.z * (y.z * inv_rms) + bv.z;
        ov.w = wv.w * (y.w * inv_rms) + bv.w;
        ((float4*)(out + (size_t)node * HIDDEN))[sub] = ov;
    }
}

extern "C" void kernel_launch(void* const* d_in, const int* in_sizes, int n_in,
                              void* d_out, int out_size, void* d_ws, size_t ws_size,
                              hipStream_t stream) {
    const float* x      = (const float*)d_in[0];
    const float* W      = (const float*)d_in[1];
    const float* b      = (const float*)d_in[2];
    const float* att_w  = (const float*)d_in[3];
    const float* norm_w = (const float*)d_in[4];
    const float* norm_b = (const float*)d_in[5];
    const int*   e      = (const int*)d_in[6];
    float* out = (float*)d_out;

    // workspace layout (floats): p[N] q[N] nacc[N]
    float* ws   = (float*)d_ws;
    float* p    = ws;
    float* q    = ws + N_NODES;
    float* nacc = ws + 2 * N_NODES;

    // Cooperative grid: co-resident blocks only. __launch_bounds__(256,4)
    // guarantees >=4 blocks/CU, so the fallback is always launchable.
    static int s_grid = 0;
    if (s_grid == 0) {
        int nb = 0;
        hipError_t err =
            hipOccupancyMaxActiveBlocksPerMultiprocessor(&nb, fused_gat, 256, 0);
        if (err != hipSuccess || nb < 1) nb = 4;
        s_grid = nb * 256;          // 256 CUs on MI355X
        if (s_grid > 2048) s_grid = 2048;
        if (s_grid < 256)  s_grid = 256;
    }

    void* args[] = {
        (void*)&x, (void*)&W, (void*)&b, (void*)&att_w,
        (void*)&norm_w, (void*)&norm_b, (void*)&e,
        (void*)&p, (void*)&q, (void*)&nacc, (void*)&out
    };
    hipLaunchCooperativeKernel((const void*)fused_gat,
                               dim3(s_grid), dim3(256),
                               args, 0, stream);
}

// Round 4
// 172.690 us; speedup vs baseline: 3.0613x; 3.0613x over previous
//
#include <hip/hip_runtime.h>

#define N_NODES 100000
#define N_EDGES 640000
#define HIDDEN  128
#define EPS     1e-6f

// ---------------------------------------------------------------------------
// Kernel 1 (fused precompute + node_dots, grid-stride):
//   Phase A (per block): u[k] = sum_j att_w[j]*W[j,k], v[k] = sum_j
//     att_w[128+j]*W[j,k] -- W is 64 KB, L2/L3-hot, so 2048 blocks
//     re-reading it costs ~134 MB of cache-hit traffic (~3 us aggregate).
//     Removes the old serialized single-block precompute kernel.
//   Phase B (grid-stride): p_i = u.x_i, q_i = v.x_i, nacc_i = 0.
//     2 nodes per wave, float4 per lane, wave reads 1 KiB contiguous.
// ---------------------------------------------------------------------------
__global__ __launch_bounds__(256) void dots_kernel(
    const float* __restrict__ x,
    const float* __restrict__ W,
    const float* __restrict__ b,
    const float* __restrict__ att_w,
    float* __restrict__ p,
    float* __restrict__ q,
    float* __restrict__ nacc)
{
    __shared__ float part_u[2][HIDDEN];
    __shared__ float part_v[2][HIDDEN];
    __shared__ __align__(16) float uv_s[2 * HIDDEN];   // u then v

    const int tid = threadIdx.x;

    // ---------------- Phase A: block-local u, v ----------------
    {
        const int k  = tid & 127;
        const int jh = tid >> 7;            // 0 or 1: which half of j-range
        float su = 0.f, sv = 0.f;
        #pragma unroll 8
        for (int jj = 0; jj < 64; ++jj) {
            int j = jh * 64 + jj;           // wave-uniform -> att_w via s_load
            float w = W[j * HIDDEN + k];    // coalesced 512B per j
            su += att_w[j] * w;
            sv += att_w[HIDDEN + j] * w;
        }
        part_u[jh][k] = su;
        part_v[jh][k] = sv;
        __syncthreads();
        if (tid < HIDDEN) {
            uv_s[tid]          = part_u[0][tid] + part_u[1][tid];
            uv_s[HIDDEN + tid] = part_v[0][tid] + part_v[1][tid];
        }
        __syncthreads();
    }

    const int lane = tid & 63;
    const int half = lane >> 5;             // which of the wave's 2 nodes
    const int sub  = lane & 31;             // float4 slot within a 128-row
    const float4 u4 = ((const float4*)uv_s)[sub];
    const float4 v4 = ((const float4*)(uv_s + HIDDEN))[sub];

    const int nwaves = (int)(gridDim.x * blockDim.x) >> 6;
    const int wid    = (int)(blockIdx.x * blockDim.x + tid) >> 6;

    // ---------------- Phase B: p, q, nacc=0 (grid-stride) ----------------
    for (int node = wid * 2 + half; node < N_NODES; node += nwaves * 2) {
        float4 xv = ((const float4*)(x + (size_t)node * HIDDEN))[sub];
        float sp = xv.x * u4.x + xv.y * u4.y + xv.z * u4.z + xv.w * u4.w;
        float sq = xv.x * v4.x + xv.y * v4.y + xv.z * v4.z + xv.w * v4.w;
        #pragma unroll
        for (int off = 16; off > 0; off >>= 1) {
            sp += __shfl_xor(sp, off);
            sq += __shfl_xor(sq, off);
        }
        if (sub == 0) {
            p[node]    = sp;
            q[node]    = sq;
            nacc[node] = 0.f;
        }
    }
}

// ---------------------------------------------------------------------------
// Kernel 1b: c = (att_w[0:128]+att_w[128:256]).b  -- one wave, overlaps K1.
// (No dependency between c and p/q; edge kernel needs both.)
// ---------------------------------------------------------------------------
__global__ void c_kernel(const float* __restrict__ b,
                         const float* __restrict__ att_w,
                         float* __restrict__ c) {
    int t0 = threadIdx.x, t1 = threadIdx.x + 64;
    float t = (att_w[t0] + att_w[HIDDEN + t0]) * b[t0]
            + (att_w[t1] + att_w[HIDDEN + t1]) * b[t1];
    #pragma unroll
    for (int off = 32; off > 0; off >>= 1) t += __shfl_xor(t, off);
    if (threadIdx.x == 0) *c = t;
}

// ---------------------------------------------------------------------------
// Kernel 2: per edge a = exp(leaky_relu(p[src]+q[dst]+c)); atomicAdd nacc[dst].
// 2 edges per thread via int4 (16B/lane coalesced edge reads).
// p/q/nacc are 400KB each -> L2-resident on every XCD.
// ---------------------------------------------------------------------------
__global__ __launch_bounds__(256) void edge_kernel(
    const int*   __restrict__ e,
    const float* __restrict__ p,
    const float* __restrict__ q,
    const float* __restrict__ c,
    float* __restrict__ nacc)
{
    int i = blockIdx.x * blockDim.x + threadIdx.x;
    if (i >= N_EDGES / 2) return;
    const float cc = c[0];
    int4 ed = ((const int4*)e)[i];          // (src0,dst0,src1,dst1)
    float s0 = p[ed.x] + q[ed.y] + cc;
    float s1 = p[ed.z] + q[ed.w] + cc;
    s0 = s0 > 0.f ? s0 : 0.2f * s0;
    s1 = s1 > 0.f ? s1 : 0.2f * s1;
    atomicAdd(&nacc[ed.y], expf(s0));
    atomicAdd(&nacc[ed.w], expf(s1));
}

// ---------------------------------------------------------------------------
// Kernel 3: y = relu(x/n') + x ; out = norm_w * y * rsqrt(mean(y^2)+eps) + norm_b
// Same 2-nodes-per-wave float4 layout.
// ---------------------------------------------------------------------------
__global__ __launch_bounds__(256) void final_kernel(
    const float* __restrict__ x,
    const float* __restrict__ nacc,
    const float* __restrict__ norm_w,
    const float* __restrict__ norm_b,
    float* __restrict__ out)
{
    int gid  = blockIdx.x * blockDim.x + threadIdx.x;
    int wave = gid >> 6;
    int lane = threadIdx.x & 63;
    int half = lane >> 5;
    int sub  = lane & 31;
    int node = wave * 2 + half;
    if (node >= N_NODES) return;

    float nn = nacc[node];
    float inv_n = 1.f / (nn == 0.f ? 1.f : nn);

    float4 xv = ((const float4*)(x + (size_t)node * HIDDEN))[sub];
    float4 y;
    {
        float h;
        h = xv.x * inv_n; h = h > 0.f ? h : 0.f; y.x = h + xv.x;
        h = xv.y * inv_n; h = h > 0.f ? h : 0.f; y.y = h + xv.y;
        h = xv.z * inv_n; h = h > 0.f ? h : 0.f; y.z = h + xv.z;
        h = xv.w * inv_n; h = h > 0.f ? h : 0.f; y.w = h + xv.w;
    }

    float ss = y.x * y.x + y.y * y.y + y.z * y.z + y.w * y.w;
    #pragma unroll
    for (int off = 16; off > 0; off >>= 1) ss += __shfl_xor(ss, off);
    float inv_rms = rsqrtf(ss * (1.f / HIDDEN) + EPS);

    float4 wv = ((const float4*)norm_w)[sub];
    float4 bv = ((const float4*)norm_b)[sub];
    float4 ov;
    ov.x = wv.x * (y.x * inv_rms) + bv.x;
    ov.y = wv.y * (y.y * inv_rms) + bv.y;
    ov.z = wv.z * (y.z * inv_rms) + bv.z;
    ov.w = wv.w * (y.w * inv_rms) + bv.w;
    ((float4*)(out + (size_t)node * HIDDEN))[sub] = ov;
}

extern "C" void kernel_launch(void* const* d_in, const int* in_sizes, int n_in,
                              void* d_out, int out_size, void* d_ws, size_t ws_size,
                              hipStream_t stream) {
    const float* x      = (const float*)d_in[0];
    const float* W      = (const float*)d_in[1];
    const float* b      = (const float*)d_in[2];
    const float* att_w  = (const float*)d_in[3];
    const float* norm_w = (const float*)d_in[4];
    const float* norm_b = (const float*)d_in[5];
    const int*   e      = (const int*)d_in[6];
    float* out = (float*)d_out;

    // workspace layout (floats): p[N] q[N] nacc[N] | c[1]
    float* ws   = (float*)d_ws;
    float* p    = ws;
    float* q    = ws + N_NODES;
    float* nacc = ws + 2 * N_NODES;
    float* c    = ws + 3 * N_NODES;

    // K1: fused u/v precompute + p/q dots. Grid-stride, 2048 blocks:
    // enough waves (8192) to saturate HBM, small enough that the per-block
    // 64 KB W re-read stays ~134 MB of L2-hit traffic.
    c_kernel<<<1, 64, 0, stream>>>(b, att_w, c);
    dots_kernel<<<2048, 256, 0, stream>>>(x, W, b, att_w, p, q, nacc);
    {
        int blocks = (N_EDGES / 2 + 255) / 256;
        edge_kernel<<<blocks, 256, 0, stream>>>(e, p, q, c, nacc);
    }
    {
        int blocks = (N_NODES + 7) / 8;
        final_kernel<<<blocks, 256, 0, stream>>>(x, nacc, norm_w, norm_b, out);
    }
}